// Round 1
// baseline (752.441 us; speedup 1.0000x reference)
//
#include <hip/hip_runtime.h>
#include <stdint.h>

#define BATCH 4096
#define DIM   1024
#define WHALF 512
#define PPREV 8

// ============================================================================
// GEMM: C[m,n] = (sum_k A[m,k]*B[n,k]) [/ L] [+ add[m,n]]
// A: [M,K] row-major, B: [N,K] row-major (i.e. C = A @ B^T)
// 64x64 tile, BK=16, 256 threads, 4x4 per thread.
// ============================================================================
template<bool DIV_L, bool HAS_ADD>
__global__ __launch_bounds__(256)
void gemm_abt(const float* __restrict__ A, const float* __restrict__ B,
              const float* __restrict__ addM, float* __restrict__ C,
              const float* __restrict__ Lptr, int M, int N, int K)
{
    __shared__ float As[16][68];   // 68: keeps float4 rows 16B-aligned, 2-way-free banks
    __shared__ float Bs[16][68];
    const int tid = threadIdx.x;
    const int m0 = blockIdx.y * 64, n0 = blockIdx.x * 64;
    const int tx = tid & 15, ty = tid >> 4;
    const int lrow = tid >> 2;          // 0..63
    const int lk   = (tid & 3) * 4;     // 0,4,8,12
    float acc[4][4] = {};

    for (int k0 = 0; k0 < K; k0 += 16) {
        float4 av = *(const float4*)(A + (size_t)(m0 + lrow) * K + k0 + lk);
        float4 bv = *(const float4*)(B + (size_t)(n0 + lrow) * K + k0 + lk);
        As[lk+0][lrow] = av.x; As[lk+1][lrow] = av.y; As[lk+2][lrow] = av.z; As[lk+3][lrow] = av.w;
        Bs[lk+0][lrow] = bv.x; Bs[lk+1][lrow] = bv.y; Bs[lk+2][lrow] = bv.z; Bs[lk+3][lrow] = bv.w;
        __syncthreads();
        #pragma unroll
        for (int k = 0; k < 16; ++k) {
            float4 a4 = *(const float4*)(&As[k][ty*4]);
            float4 b4 = *(const float4*)(&Bs[k][tx*4]);
            acc[0][0] += a4.x*b4.x; acc[0][1] += a4.x*b4.y; acc[0][2] += a4.x*b4.z; acc[0][3] += a4.x*b4.w;
            acc[1][0] += a4.y*b4.x; acc[1][1] += a4.y*b4.y; acc[1][2] += a4.y*b4.z; acc[1][3] += a4.y*b4.w;
            acc[2][0] += a4.z*b4.x; acc[2][1] += a4.z*b4.y; acc[2][2] += a4.z*b4.z; acc[2][3] += a4.z*b4.w;
            acc[3][0] += a4.w*b4.x; acc[3][1] += a4.w*b4.y; acc[3][2] += a4.w*b4.z; acc[3][3] += a4.w*b4.w;
        }
        __syncthreads();
    }

    float Lv = DIV_L ? *Lptr : 1.0f;
    #pragma unroll
    for (int i = 0; i < 4; ++i) {
        #pragma unroll
        for (int j = 0; j < 4; ++j) {
            size_t o = (size_t)(m0 + ty*4 + i) * N + (n0 + tx*4 + j);
            float r = acc[i][j];
            if (DIV_L) r = r / Lv;
            if (HAS_ADD) r += addM[o];
            C[o] = r;
        }
    }
}

// ============================================================================
// Exact per-row top-10 by |value| with jax.lax.top_k tie-break (lower index
// wins among equal values). One wave (64 lanes) per row; row element j owned
// by lane (j & 63), slot (j >> 6). Key = (|c|bits << 10) | (1023 - j): uint64
// max-compare == (value desc, index asc).
// ============================================================================
__device__ __forceinline__ void wave_top10(const float cz[16], int lane,
                                           int wi[10], float wv[10])
{
    uint64_t lk[10]; float lv[10];
    #pragma unroll
    for (int t = 0; t < 10; ++t) { lk[t] = 0ull; lv[t] = 0.0f; }

    // build per-lane sorted (desc) top-10 of this lane's 16 elements
    #pragma unroll
    for (int s = 0; s < 16; ++s) {
        const int j = lane + (s << 6);
        const float c = cz[s];
        const uint32_t u = __float_as_uint(c) & 0x7fffffffu;
        const uint64_t key = (((uint64_t)u) << 10) | (uint64_t)(1023 - j);
        if (key > lk[9]) {
            lk[9] = key; lv[9] = c;
            #pragma unroll
            for (int t = 9; t >= 1; --t) {
                if (lk[t] > lk[t-1]) {
                    uint64_t tk = lk[t]; lk[t] = lk[t-1]; lk[t-1] = tk;
                    float    tv = lv[t]; lv[t] = lv[t-1]; lv[t-1] = tv;
                }
            }
        }
    }

    // 10 rounds of wave-wide argmax over list heads
    #pragma unroll
    for (int r = 0; r < 10; ++r) {
        unsigned long long key = (unsigned long long)lk[0];
        float val = lv[0];
        #pragma unroll
        for (int m = 1; m < 64; m <<= 1) {
            unsigned long long ok = __shfl_xor(key, m);
            float ov = __shfl_xor(val, m);
            if (ok > key) { key = ok; val = ov; }
        }
        wi[r] = 1023 - (int)(key & 1023ull);
        wv[r] = val;
        if ((unsigned long long)lk[0] == key) {   // this lane owned the winner: pop head
            #pragma unroll
            for (int t = 0; t < 9; ++t) { lk[t] = lk[t+1]; lv[t] = lv[t+1]; }
            lk[9] = 0ull; lv[9] = 0.0f;
        }
    }
}

// ============================================================================
// Warm-up: z=hard_thr(b); c=b+z@S^T (sparse, S symmetric -> row reads);
// z=hard_thr(c) -> store sparse (idx,val). One wave per row, 4 rows/block.
// ============================================================================
__global__ __launch_bounds__(256)
void warmup_rows(const float* __restrict__ b, const float* __restrict__ S,
                 int* __restrict__ sidx, float* __restrict__ sval)
{
    const int tid = threadIdx.x;
    const int lane = tid & 63;
    const int r = blockIdx.x * 4 + (tid >> 6);
    const float* bp = b + (size_t)r * DIM;

    float bz[16], cz[16];
    #pragma unroll
    for (int s = 0; s < 16; ++s) bz[s] = bp[lane + (s << 6)];

    int wi[10]; float wv[10];
    wave_top10(bz, lane, wi, wv);

    #pragma unroll
    for (int s = 0; s < 16; ++s) {
        float a = bz[s];
        #pragma unroll
        for (int k = 0; k < 10; ++k)
            a += wv[k] * S[(size_t)wi[k] * DIM + lane + (s << 6)];
        cz[s] = a;
    }
    wave_top10(cz, lane, wi, wv);

    if (lane == 0) {
        #pragma unroll
        for (int k = 0; k < 10; ++k) { sidx[r*10+k] = wi[k]; sval[r*10+k] = wv[k]; }
    }
}

// ============================================================================
// Main loop: z=hard_thr(c1), then 9 x { c=b+z@S^T (sparse); z=hard_thr(c) }.
// Writes dense z row to zout (zout may alias c1: row fully read before write)
// and sparse (idx,val) for the final spectral density.
// ============================================================================
__global__ __launch_bounds__(256)
void loop_rows(const float* __restrict__ c1, const float* __restrict__ b,
               const float* __restrict__ S, float* __restrict__ zout,
               int* __restrict__ sidx, float* __restrict__ sval)
{
    const int tid = threadIdx.x;
    const int lane = tid & 63;
    const int r = blockIdx.x * 4 + (tid >> 6);
    const float* bp = b  + (size_t)r * DIM;
    const float* cp = c1 + (size_t)r * DIM;

    float bz[16], cz[16];
    #pragma unroll
    for (int s = 0; s < 16; ++s) { bz[s] = bp[lane+(s<<6)]; cz[s] = cp[lane+(s<<6)]; }

    int wi[10]; float wv[10];
    wave_top10(cz, lane, wi, wv);

    for (int it = 0; it < 9; ++it) {
        #pragma unroll
        for (int s = 0; s < 16; ++s) {
            float a = bz[s];
            #pragma unroll
            for (int k = 0; k < 10; ++k)
                a += wv[k] * S[(size_t)wi[k] * DIM + lane + (s << 6)];
            cz[s] = a;
        }
        wave_top10(cz, lane, wi, wv);
    }

    #pragma unroll
    for (int s = 0; s < 16; ++s) {
        const int j = lane + (s << 6);
        float v = 0.0f;
        #pragma unroll
        for (int k = 0; k < 10; ++k) v = (j == wi[k]) ? wv[k] : v;
        zout[(size_t)r * DIM + j] = v;
    }
    if (lane == 0) {
        #pragma unroll
        for (int k = 0; k < 10; ++k) { sidx[r*10+k] = wi[k]; sval[r*10+k] = wv[k]; }
    }
}

// ============================================================================
// Spectral density from sparse z: deterministic two-stage reduction.
// ============================================================================
__global__ void sparse_density_stage1(const int* __restrict__ sidx,
                                      const float* __restrict__ sval,
                                      float* __restrict__ partial)  // [64][512]
{
    const int w = threadIdx.x;            // 512
    const int blk = blockIdx.x;           // 64 blocks x 64 rows
    const int base = blk * 64 * 10;
    float acc = 0.0f;
    for (int e = 0; e < 640; ++e) {
        int d = sidx[base + e];
        float v = sval[base + e];
        if ((d & 511) == w) acc += v * v;
    }
    partial[blk * 512 + w] = acc;
}

__global__ void density_stage2(const float* __restrict__ partial, float* __restrict__ mD)
{
    const int w = threadIdx.x;
    float acc = 0.0f;
    for (int i = 0; i < 64; ++i) acc += partial[i * 512 + w];
    mD[w] = acc;
}

// ============================================================================
// prev_windows spectral density: mD_prev[p,w] = sum_r pw[p,r,w]^2 + pw[p,r,w+512]^2
// ============================================================================
__global__ void prev_density_stage1(const float* __restrict__ pw, float* __restrict__ partial)
{
    const int p = blockIdx.x, chunk = blockIdx.y;   // (8, 64)
    const int w = threadIdx.x;                      // 512
    const float* base = pw + ((size_t)p * BATCH + (size_t)chunk * 64) * DIM;
    float acc = 0.0f;
    for (int i = 0; i < 64; ++i) {
        float a = base[(size_t)i * DIM + w];
        float c = base[(size_t)i * DIM + 512 + w];
        acc += a * a + c * c;
    }
    partial[((size_t)(p * 64 + chunk)) * 512 + w] = acc;
}

__global__ void prev_density_stage2(const float* __restrict__ partial, float* __restrict__ mD_prev)
{
    const int p = blockIdx.x; const int w = threadIdx.x;
    float acc = 0.0f;
    for (int i = 0; i < 64; ++i) acc += partial[((size_t)(p * 64 + i)) * 512 + w];
    mD_prev[p * 512 + w] = acc;
}

// ============================================================================
// Normalize densities, attention logits, softmax -> att[8]. Single block.
// ============================================================================
__global__ void attention_small(const float* __restrict__ mD1,
                                const float* __restrict__ mD_prev,
                                float* __restrict__ att)
{
    __shared__ float red[512];
    __shared__ float att_l[PPREV];
    const int tid = threadIdx.x;
    float v = mD1[tid];

    red[tid] = v; __syncthreads();
    for (int off = 256; off > 0; off >>= 1) { if (tid < off) red[tid] = fmaxf(red[tid], red[tid+off]); __syncthreads(); }
    float mx = red[0]; __syncthreads();
    red[tid] = v; __syncthreads();
    for (int off = 256; off > 0; off >>= 1) { if (tid < off) red[tid] = fminf(red[tid], red[tid+off]); __syncthreads(); }
    float mn = red[0]; __syncthreads();
    const float mDn_t = (v - mn) / (mx - mn + 1e-8f);

    for (int p = 0; p < PPREV; ++p) {
        float u = mD_prev[p * 512 + tid];
        red[tid] = u; __syncthreads();
        for (int off = 256; off > 0; off >>= 1) { if (tid < off) red[tid] = fmaxf(red[tid], red[tid+off]); __syncthreads(); }
        float px = red[0]; __syncthreads();
        red[tid] = u; __syncthreads();
        for (int off = 256; off > 0; off >>= 1) { if (tid < off) red[tid] = fminf(red[tid], red[tid+off]); __syncthreads(); }
        float pn = red[0]; __syncthreads();
        float un = (u - pn) / (px - pn + 1e-8f);
        red[tid] = un * mDn_t; __syncthreads();
        for (int off = 256; off > 0; off >>= 1) { if (tid < off) red[tid] += red[tid+off]; __syncthreads(); }
        if (tid == 0) att_l[p] = red[0] / 22.627417f;   // np.float32(sqrt(512))
        __syncthreads();
    }

    if (tid == 0) {
        float m = att_l[0];
        for (int p = 1; p < PPREV; ++p) m = fmaxf(m, att_l[p]);
        float e[PPREV], s = 0.0f;
        for (int p = 0; p < PPREV; ++p) { e[p] = expf(att_l[p] - m); s += e[p]; }
        for (int p = 0; p < PPREV; ++p) att[p] = e[p] / s;
    }
}

// ============================================================================
// z_att = lambda2 * sum_p clip(pw[p], +-150) * att[p]
// ============================================================================
__global__ __launch_bounds__(256)
void weighted_sum(const float* __restrict__ pw, const float* __restrict__ att,
                  const float* __restrict__ lam, float* __restrict__ zatt)
{
    const size_t i = ((size_t)blockIdx.x * 256 + threadIdx.x) * 4;
    const float l2 = *lam;
    float a[PPREV];
    #pragma unroll
    for (int p = 0; p < PPREV; ++p) a[p] = att[p];
    float4 acc = make_float4(0.f, 0.f, 0.f, 0.f);
    #pragma unroll
    for (int p = 0; p < PPREV; ++p) {
        float4 v = *(const float4*)(pw + (size_t)p * BATCH * DIM + i);
        v.x = fminf(fmaxf(v.x, -150.f), 150.f);
        v.y = fminf(fmaxf(v.y, -150.f), 150.f);
        v.z = fminf(fmaxf(v.z, -150.f), 150.f);
        v.w = fminf(fmaxf(v.w, -150.f), 150.f);
        acc.x += v.x * a[p]; acc.y += v.y * a[p]; acc.z += v.z * a[p]; acc.w += v.w * a[p];
    }
    acc.x *= l2; acc.y *= l2; acc.z *= l2; acc.w *= l2;
    *(float4*)(zatt + i) = acc;
}

// ============================================================================
// Final min-max normalize of mD2 into out[0:512]
// ============================================================================
__global__ void finalize(const float* __restrict__ mD, float* __restrict__ out)
{
    __shared__ float red[512];
    const int tid = threadIdx.x;
    float v = mD[tid];
    red[tid] = v; __syncthreads();
    for (int off = 256; off > 0; off >>= 1) { if (tid < off) red[tid] = fmaxf(red[tid], red[tid+off]); __syncthreads(); }
    float mx = red[0]; __syncthreads();
    red[tid] = v; __syncthreads();
    for (int off = 256; off > 0; off >>= 1) { if (tid < off) red[tid] = fminf(red[tid], red[tid+off]); __syncthreads(); }
    float mn = red[0];
    out[tid] = (v - mn) / (mx - mn + 1e-8f);
}

// ============================================================================
extern "C" void kernel_launch(void* const* d_in, const int* in_sizes, int n_in,
                              void* d_out, int out_size, void* d_ws, size_t ws_size,
                              hipStream_t stream)
{
    const float* x   = (const float*)d_in[0];   // [4096,1024]
    const float* pw  = (const float*)d_in[1];   // [8,4096,1024]
    const float* Wd  = (const float*)d_in[2];   // [1,1024,1024]
    const float* S   = (const float*)d_in[3];   // [1,1024,1024] (numerically symmetric)
    const float* lam = (const float*)d_in[4];   // scalar
    const float* L   = (const float*)d_in[5];   // scalar
    float* out = (float*)d_out;                 // [512] ++ [4096*1024]

    // workspace layout (floats) ~35 MB
    float* b       = (float*)d_ws;                      // 4,194,304
    float* zatt    = b + (size_t)BATCH * DIM;           // 4,194,304
    float* pp_prev = zatt + (size_t)BATCH * DIM;        // 8*64*512 = 262,144
    float* pp_dens = pp_prev + 262144;                  // 64*512   =  32,768
    float* mD1     = pp_dens + 32768;                   // 512
    float* mD_prev = mD1 + 512;                         // 4096
    float* attw    = mD_prev + 4096;                    // 8
    float* mD2     = attw + 8;                          // 512
    float* sval1   = mD2 + 512;                         // 40,960
    float* sval2   = sval1 + 40960;                     // 40,960
    int*   sidx1   = (int*)(sval2 + 40960);             // 40,960 ints
    int*   sidx2   = sidx1 + 40960;                     // 40,960 ints

    float* c1   = out + 512;   // stage c1 in the output z region (rewritten by loop_rows)
    float* zout = out + 512;

    const dim3 gg(DIM / 64, BATCH / 64);   // (16, 64)

    // b = x @ Wd^T / L
    gemm_abt<true,  false><<<gg, 256, 0, stream>>>(x, Wd, nullptr, b, L, BATCH, DIM, DIM);
    // warm-up ISTA steps -> sparse z, spectral density mD1
    warmup_rows<<<BATCH / 4, 256, 0, stream>>>(b, S, sidx1, sval1);
    sparse_density_stage1<<<64, 512, 0, stream>>>(sidx1, sval1, pp_dens);
    density_stage2<<<1, 512, 0, stream>>>(pp_dens, mD1);
    // prev-window densities
    prev_density_stage1<<<dim3(PPREV, 64), 512, 0, stream>>>(pw, pp_prev);
    prev_density_stage2<<<PPREV, 512, 0, stream>>>(pp_prev, mD_prev);
    // attention weights
    attention_small<<<1, 512, 0, stream>>>(mD1, mD_prev, attw);
    // z_att = lambda2 * sum_p clip(pw)*att
    weighted_sum<<<(BATCH * DIM) / 1024, 256, 0, stream>>>(pw, attw, lam, zatt);
    // loop iteration 1 (dense z): c1 = b + z_att @ S^T
    gemm_abt<false, true ><<<gg, 256, 0, stream>>>(zatt, S, b, c1, nullptr, BATCH, DIM, DIM);
    // iterations 1..10 thresholding + sparse updates; writes dense z to out
    loop_rows<<<BATCH / 4, 256, 0, stream>>>(c1, b, S, zout, sidx2, sval2);
    // final spectral density -> out[0:512]
    sparse_density_stage1<<<64, 512, 0, stream>>>(sidx2, sval2, pp_dens);
    density_stage2<<<1, 512, 0, stream>>>(pp_dens, mD2);
    finalize<<<1, 512, 0, stream>>>(mD2, out);
}

// Round 2
// 581.063 us; speedup vs baseline: 1.2949x; 1.2949x over previous
//
#include <hip/hip_runtime.h>
#include <stdint.h>

#define BATCH 4096
#define DIM   1024
#define PPREV 8

// ============================================================================
// Wave (64-lane) helpers
// ============================================================================
__device__ __forceinline__ int wave_max_i32(int v) {
    #pragma unroll
    for (int m = 1; m < 64; m <<= 1) v = max(v, __shfl_xor(v, m));
    return v;
}
__device__ __forceinline__ int wave_min_i32(int v) {
    #pragma unroll
    for (int m = 1; m < 64; m <<= 1) v = min(v, __shfl_xor(v, m));
    return v;
}
__device__ __forceinline__ int wave_sum_i32(int v) {
    #pragma unroll
    for (int m = 1; m < 64; m <<= 1) v += __shfl_xor(v, m);
    return v;
}
__device__ __forceinline__ int wave_exscan_i32(int v, int lane) {
    int s = v;
    #pragma unroll
    for (int off = 1; off < 64; off <<= 1) {
        int o = __shfl_up(s, off);
        s += (lane >= off) ? o : 0;
    }
    return s - v;
}

// ============================================================================
// Top-10 selection by |value| with exact jax.lax.top_k tie-break (lowest flat
// index wins among equal values). Element j of a row is owned by lane (j>>4),
// slot (j&15)  [lane-major mapping: j = lane*16 + s].
// Keys are |f32 bits| as int (positive => int compare == float-magnitude
// compare).
// ============================================================================

// Valid lower bound on the 10th-largest |value|: the 10th-largest of the 64
// per-lane maxima (10 distinct lanes each hold an element >= t).
__device__ __forceinline__ int bound10_tbits(const int k[16], int lane) {
    int lm = k[0];
    #pragma unroll
    for (int s = 1; s < 16; ++s) lm = max(lm, k[s]);
    int cur = lm, tb = 0;
    #pragma unroll
    for (int r = 0; r < 10; ++r) {
        int m = wave_max_i32(cur);
        tb = m;
        unsigned long long ball = __ballot(cur == m);
        int wl = (int)__ffsll(ball) - 1;
        if (lane == wl) cur = 0;
    }
    return tb;
}

// Always-correct fallback: 10 rounds of wave-wide argmax with exact (value
// desc, index asc) order over all 1024 elements. ~rare path.
__device__ __forceinline__ void top10_full(const int kin[16], int sgn, int lane,
                                           int wi[10], float wv[10]) {
    int k[16];
    #pragma unroll
    for (int s = 0; s < 16; ++s) k[s] = kin[s];
    #pragma unroll
    for (int r = 0; r < 10; ++r) {
        int lm = k[0]; int ls = 0;
        #pragma unroll
        for (int s = 1; s < 16; ++s) { if (k[s] > lm) { lm = k[s]; ls = s; } }
        int m = wave_max_i32(lm);
        int cj = (lm == m) ? ((lane << 4) | ls) : 4096;
        int jw = wave_min_i32(cj);
        int wl = jw >> 4, ws = jw & 15;
        int sg = __shfl(sgn, wl);
        wi[r] = jw;
        wv[r] = __int_as_float(m | (((sg >> ws) & 1) << 31));
        if (lane == wl) {
            #pragma unroll
            for (int s = 0; s < 16; ++s) if (s == ws) k[s] = 0;
        }
    }
}

// Fast path: candidates >= t compacted to one-per-lane, then 10 single-element
// pop rounds (exact tie-break preserved). Returns false if >64 candidates.
__device__ __forceinline__ bool top10_pruned(const float cz[16], const int k[16], int lane,
                                             float* svalw, int* sjw,
                                             int& tbits, int wi[10], float wv[10]) {
    int tb = tbits;
    int total;
    #pragma unroll 1
    for (int attempt = 0; ; ++attempt) {
        int c = 0;
        #pragma unroll
        for (int s = 0; s < 16; ++s) c += (k[s] >= tb) ? 1 : 0;
        total = wave_sum_i32(c);
        if (total >= 10) break;
        tb = (tb > 0x00800000) ? (tb - 0x00800000) : 0;   // halve threshold
        if (attempt >= 20) tb = 0;
    }
    if (total > 64) return false;
    int cnt = 0;
    #pragma unroll
    for (int s = 0; s < 16; ++s) cnt += (k[s] >= tb) ? 1 : 0;
    int p = wave_exscan_i32(cnt, lane);
    #pragma unroll
    for (int s = 0; s < 16; ++s) {
        if (k[s] >= tb) { svalw[p] = cz[s]; sjw[p] = (lane << 4) | s; ++p; }
    }
    asm volatile("s_waitcnt lgkmcnt(0)" ::: "memory");
    float mv = 0.0f; int mj = 4096; int mk = 0;
    if (lane < total) { mv = svalw[lane]; mj = sjw[lane]; mk = __float_as_int(mv) & 0x7fffffff; }
    #pragma unroll
    for (int r = 0; r < 10; ++r) {
        int m = wave_max_i32(mk);
        int cj = (mk == m) ? mj : 4096;
        int jw = wave_min_i32(cj);
        unsigned long long ball = __ballot(mj == jw);
        int wl = (int)__ffsll(ball) - 1;
        wv[r] = __shfl(mv, wl);
        wi[r] = jw;
        mk = (mj == jw) ? 0 : mk;
    }
    tbits = __float_as_int(wv[9]) & 0x7fffffff;
    return true;
}

__device__ __forceinline__ void select10(const float cz[16], int lane,
                                         float* svalw, int* sjw,
                                         int& tbits, bool seeded,
                                         int wi[10], float wv[10]) {
    int k[16]; int sgn = 0;
    #pragma unroll
    for (int s = 0; s < 16; ++s) {
        int bb = __float_as_int(cz[s]);
        k[s] = bb & 0x7fffffff;
        sgn |= (int)(((unsigned)bb >> 31) << s);
    }
    if (!seeded) tbits = bound10_tbits(k, lane);
    if (!top10_pruned(cz, k, lane, svalw, sjw, tbits, wi, wv)) {
        top10_full(k, sgn, lane, wi, wv);
        tbits = __float_as_int(wv[9]) & 0x7fffffff;
    }
}

// c = b + sum_k wv[k] * S[wi[k], :]   (S numerically symmetric; row access)
__device__ __forceinline__ void gather_ista(const float bz[16], float cz[16],
                                            const float* __restrict__ S,
                                            const int wi[10], const float wv[10], int lane) {
    #pragma unroll
    for (int s = 0; s < 16; ++s) cz[s] = bz[s];
    #pragma unroll
    for (int kk = 0; kk < 10; ++kk) {
        int row = __builtin_amdgcn_readfirstlane(wi[kk]);
        float wvs = __int_as_float(__builtin_amdgcn_readfirstlane(__float_as_int(wv[kk])));
        const float4* sp = (const float4*)(S + (size_t)row * DIM + (lane << 4));
        #pragma unroll
        for (int q = 0; q < 4; ++q) {
            float4 v = sp[q];
            cz[q*4+0] += wvs * v.x;
            cz[q*4+1] += wvs * v.y;
            cz[q*4+2] += wvs * v.z;
            cz[q*4+3] += wvs * v.w;
        }
    }
}

// ============================================================================
// Warm-up: z=thr(b); c=b+z@S^T; z=thr(c) -> sparse (idx,val). 1 wave/row.
// ============================================================================
__global__ __launch_bounds__(256)
void warmup_rows(const float* __restrict__ b, const float* __restrict__ S,
                 int* __restrict__ sidx, float* __restrict__ sval) {
    __shared__ float s_v[4][64];
    __shared__ int   s_j[4][64];
    const int tid = threadIdx.x, lane = tid & 63, wid = tid >> 6;
    const int r = blockIdx.x * 4 + wid;
    const float* bp = b + (size_t)r * DIM + (lane << 4);
    float bz[16];
    #pragma unroll
    for (int q = 0; q < 4; ++q) {
        float4 v = ((const float4*)bp)[q];
        bz[q*4+0] = v.x; bz[q*4+1] = v.y; bz[q*4+2] = v.z; bz[q*4+3] = v.w;
    }
    int wi[10]; float wv[10]; int tbits = 0;
    select10(bz, lane, s_v[wid], s_j[wid], tbits, false, wi, wv);
    float cz[16];
    gather_ista(bz, cz, S, wi, wv, lane);
    select10(cz, lane, s_v[wid], s_j[wid], tbits, true, wi, wv);
    if (lane == 0) {
        #pragma unroll
        for (int kk = 0; kk < 10; ++kk) { sidx[r*10+kk] = wi[kk]; sval[r*10+kk] = wv[kk]; }
    }
}

// ============================================================================
// Main loop: z=thr(c1); 9 x { c=b+z@S^T; z=thr(c) }. Writes dense z + sparse.
// ============================================================================
__global__ __launch_bounds__(256)
void loop_rows(const float* __restrict__ c1, const float* __restrict__ b,
               const float* __restrict__ S, float* __restrict__ zout,
               int* __restrict__ sidx, float* __restrict__ sval) {
    __shared__ float s_v[4][64];
    __shared__ int   s_j[4][64];
    const int tid = threadIdx.x, lane = tid & 63, wid = tid >> 6;
    const int r = blockIdx.x * 4 + wid;
    const float* bp = b  + (size_t)r * DIM + (lane << 4);
    const float* cp = c1 + (size_t)r * DIM + (lane << 4);
    float bz[16], cz[16];
    #pragma unroll
    for (int q = 0; q < 4; ++q) {
        float4 v = ((const float4*)bp)[q];
        bz[q*4+0] = v.x; bz[q*4+1] = v.y; bz[q*4+2] = v.z; bz[q*4+3] = v.w;
        float4 u = ((const float4*)cp)[q];
        cz[q*4+0] = u.x; cz[q*4+1] = u.y; cz[q*4+2] = u.z; cz[q*4+3] = u.w;
    }
    int wi[10]; float wv[10]; int tbits = 0;
    select10(cz, lane, s_v[wid], s_j[wid], tbits, false, wi, wv);
    #pragma unroll 1
    for (int it = 0; it < 9; ++it) {
        gather_ista(bz, cz, S, wi, wv, lane);
        select10(cz, lane, s_v[wid], s_j[wid], tbits, true, wi, wv);
    }
    // dense z write (zout may alias c1: same thread covers same addresses)
    #pragma unroll
    for (int q = 0; q < 4; ++q) {
        float e[4];
        #pragma unroll
        for (int t = 0; t < 4; ++t) {
            int j = (lane << 4) | (q*4 + t);
            float v = 0.0f;
            #pragma unroll
            for (int kk = 0; kk < 10; ++kk) v = (wi[kk] == j) ? wv[kk] : v;
            e[t] = v;
        }
        float4 o; o.x = e[0]; o.y = e[1]; o.z = e[2]; o.w = e[3];
        ((float4*)(zout + (size_t)r * DIM + (lane << 4)))[q] = o;
    }
    if (lane == 0) {
        #pragma unroll
        for (int kk = 0; kk < 10; ++kk) { sidx[r*10+kk] = wi[kk]; sval[r*10+kk] = wv[kk]; }
    }
}

// ============================================================================
// GEMM: C[m,n] = (sum_k A[m,k]*B[n,k]) [/L] [+ add[m,n]]  (C = A @ B^T)
// 128x128 tile, BK=16, 512 threads, 4x8 per thread.
// ============================================================================
template<bool DIV_L, bool HAS_ADD>
__global__ __launch_bounds__(512)
void gemm128(const float* __restrict__ A, const float* __restrict__ B,
             const float* __restrict__ addM, float* __restrict__ C,
             const float* __restrict__ Lptr, int M, int N, int K) {
    __shared__ float As[16][132];
    __shared__ float Bs[16][132];
    const int tid = threadIdx.x;
    const int m0 = blockIdx.y * 128, n0 = blockIdx.x * 128;
    const int tx = tid & 15;          // n-group (8 wide)
    const int ty = tid >> 4;          // m-group (4 wide), 0..31
    const int srow = tid >> 2;        // staging row 0..127
    const int sk   = (tid & 3) * 4;   // staging k 0,4,8,12
    float acc[4][8] = {};
    const float* Ab = A + (size_t)(m0 + srow) * K + sk;
    const float* Bb = B + (size_t)(n0 + srow) * K + sk;
    for (int k0 = 0; k0 < K; k0 += 16) {
        float4 av = *(const float4*)(Ab + k0);
        float4 bv = *(const float4*)(Bb + k0);
        __syncthreads();
        As[sk+0][srow] = av.x; As[sk+1][srow] = av.y; As[sk+2][srow] = av.z; As[sk+3][srow] = av.w;
        Bs[sk+0][srow] = bv.x; Bs[sk+1][srow] = bv.y; Bs[sk+2][srow] = bv.z; Bs[sk+3][srow] = bv.w;
        __syncthreads();
        #pragma unroll
        for (int k = 0; k < 16; ++k) {
            float4 a4  = *(const float4*)&As[k][ty*4];
            float4 b40 = *(const float4*)&Bs[k][tx*8];
            float4 b41 = *(const float4*)&Bs[k][tx*8+4];
            float am[4] = {a4.x, a4.y, a4.z, a4.w};
            float bn[8] = {b40.x, b40.y, b40.z, b40.w, b41.x, b41.y, b41.z, b41.w};
            #pragma unroll
            for (int i = 0; i < 4; ++i)
                #pragma unroll
                for (int j = 0; j < 8; ++j)
                    acc[i][j] += am[i] * bn[j];
        }
    }
    const float invL = DIV_L ? (1.0f / *Lptr) : 1.0f;
    #pragma unroll
    for (int i = 0; i < 4; ++i) {
        size_t row = (size_t)(m0 + ty*4 + i);
        float* Cp = C + row * N + n0 + tx*8;
        #pragma unroll
        for (int j = 0; j < 8; ++j) {
            float r = acc[i][j];
            if (DIV_L) r *= invL;
            if (HAS_ADD) r += addM[row * N + n0 + tx*8 + j];
            Cp[j] = r;
        }
    }
}

// ============================================================================
// Spectral density from sparse z (deterministic two-stage)
// ============================================================================
__global__ void sparse_density_stage1(const int* __restrict__ sidx,
                                      const float* __restrict__ sval,
                                      float* __restrict__ partial) {
    const int w = threadIdx.x;            // 512
    const int blk = blockIdx.x;           // 64 blocks x 64 rows
    const int base = blk * 64 * 10;
    float acc = 0.0f;
    for (int e = 0; e < 640; ++e) {
        int d = sidx[base + e];
        float v = sval[base + e];
        if ((d & 511) == w) acc += v * v;
    }
    partial[blk * 512 + w] = acc;
}

__global__ void density_stage2(const float* __restrict__ partial, float* __restrict__ mD) {
    const int w = threadIdx.x;
    float acc = 0.0f;
    for (int i = 0; i < 64; ++i) acc += partial[i * 512 + w];
    mD[w] = acc;
}

// ============================================================================
// prev_windows spectral density
// ============================================================================
__global__ void prev_density_stage1(const float* __restrict__ pw, float* __restrict__ partial) {
    const int p = blockIdx.x, chunk = blockIdx.y;   // (8, 64)
    const int w = threadIdx.x;                      // 512
    const float* base = pw + ((size_t)p * BATCH + (size_t)chunk * 64) * DIM;
    float acc = 0.0f;
    for (int i = 0; i < 64; ++i) {
        float a = base[(size_t)i * DIM + w];
        float c = base[(size_t)i * DIM + 512 + w];
        acc += a * a + c * c;
    }
    partial[((size_t)(p * 64 + chunk)) * 512 + w] = acc;
}

__global__ void prev_density_stage2(const float* __restrict__ partial, float* __restrict__ mD_prev) {
    const int p = blockIdx.x; const int w = threadIdx.x;
    float acc = 0.0f;
    for (int i = 0; i < 64; ++i) acc += partial[((size_t)(p * 64 + i)) * 512 + w];
    mD_prev[p * 512 + w] = acc;
}

// ============================================================================
// Attention: one wave per prev-window, shfl reductions, single barrier.
// ============================================================================
__device__ __forceinline__ float wave_fmax(float v) {
    #pragma unroll
    for (int m = 1; m < 64; m <<= 1) v = fmaxf(v, __shfl_xor(v, m));
    return v;
}
__device__ __forceinline__ float wave_fmin(float v) {
    #pragma unroll
    for (int m = 1; m < 64; m <<= 1) v = fminf(v, __shfl_xor(v, m));
    return v;
}
__device__ __forceinline__ float wave_fsum(float v) {
    #pragma unroll
    for (int m = 1; m < 64; m <<= 1) v += __shfl_xor(v, m);
    return v;
}

__global__ void attention_small(const float* __restrict__ mD1,
                                const float* __restrict__ mD_prev,
                                float* __restrict__ att) {
    __shared__ float att_l[PPREV];
    const int tid = threadIdx.x, lane = tid & 63, w = tid >> 6;   // 512 thr, 8 waves
    float t8[8], u8[8];
    {
        const float4* m4 = (const float4*)(mD1 + lane * 8);
        float4 a = m4[0], bq = m4[1];
        t8[0]=a.x; t8[1]=a.y; t8[2]=a.z; t8[3]=a.w; t8[4]=bq.x; t8[5]=bq.y; t8[6]=bq.z; t8[7]=bq.w;
        const float4* p4 = (const float4*)(mD_prev + w * 512 + lane * 8);
        float4 c = p4[0], d = p4[1];
        u8[0]=c.x; u8[1]=c.y; u8[2]=c.z; u8[3]=c.w; u8[4]=d.x; u8[5]=d.y; u8[6]=d.z; u8[7]=d.w;
    }
    float mx = t8[0], mn = t8[0], pmx = u8[0], pmn = u8[0];
    #pragma unroll
    for (int i = 1; i < 8; ++i) {
        mx = fmaxf(mx, t8[i]); mn = fminf(mn, t8[i]);
        pmx = fmaxf(pmx, u8[i]); pmn = fminf(pmn, u8[i]);
    }
    mx = wave_fmax(mx); mn = wave_fmin(mn);
    pmx = wave_fmax(pmx); pmn = wave_fmin(pmn);
    const float inv  = 1.0f / (mx - mn + 1e-8f);
    const float pinv = 1.0f / (pmx - pmn + 1e-8f);
    float dot = 0.0f;
    #pragma unroll
    for (int i = 0; i < 8; ++i) dot += ((u8[i] - pmn) * pinv) * ((t8[i] - mn) * inv);
    dot = wave_fsum(dot);
    if (lane == 0) att_l[w] = dot / 22.627417f;   // np.float32(sqrt(512))
    __syncthreads();
    if (tid == 0) {
        float m = att_l[0];
        #pragma unroll
        for (int p = 1; p < PPREV; ++p) m = fmaxf(m, att_l[p]);
        float e[PPREV], s = 0.0f;
        #pragma unroll
        for (int p = 0; p < PPREV; ++p) { e[p] = expf(att_l[p] - m); s += e[p]; }
        #pragma unroll
        for (int p = 0; p < PPREV; ++p) att[p] = e[p] / s;
    }
}

// ============================================================================
// z_att = lambda2 * sum_p clip(pw[p], +-150) * att[p]
// ============================================================================
__global__ __launch_bounds__(256)
void weighted_sum(const float* __restrict__ pw, const float* __restrict__ att,
                  const float* __restrict__ lam, float* __restrict__ zatt) {
    const size_t i = ((size_t)blockIdx.x * 256 + threadIdx.x) * 4;
    const float l2 = *lam;
    float a[PPREV];
    #pragma unroll
    for (int p = 0; p < PPREV; ++p) a[p] = att[p];
    float4 acc = make_float4(0.f, 0.f, 0.f, 0.f);
    #pragma unroll
    for (int p = 0; p < PPREV; ++p) {
        float4 v = *(const float4*)(pw + (size_t)p * BATCH * DIM + i);
        v.x = fminf(fmaxf(v.x, -150.f), 150.f);
        v.y = fminf(fmaxf(v.y, -150.f), 150.f);
        v.z = fminf(fmaxf(v.z, -150.f), 150.f);
        v.w = fminf(fmaxf(v.w, -150.f), 150.f);
        acc.x += v.x * a[p]; acc.y += v.y * a[p]; acc.z += v.z * a[p]; acc.w += v.w * a[p];
    }
    acc.x *= l2; acc.y *= l2; acc.z *= l2; acc.w *= l2;
    *(float4*)(zatt + i) = acc;
}

// ============================================================================
// Final min-max normalize of mD2 into out[0:512]
// ============================================================================
__global__ void finalize(const float* __restrict__ mD, float* __restrict__ out) {
    __shared__ float red[512];
    const int tid = threadIdx.x;
    float v = mD[tid];
    red[tid] = v; __syncthreads();
    for (int off = 256; off > 0; off >>= 1) { if (tid < off) red[tid] = fmaxf(red[tid], red[tid+off]); __syncthreads(); }
    float mx = red[0]; __syncthreads();
    red[tid] = v; __syncthreads();
    for (int off = 256; off > 0; off >>= 1) { if (tid < off) red[tid] = fminf(red[tid], red[tid+off]); __syncthreads(); }
    float mn = red[0];
    out[tid] = (v - mn) / (mx - mn + 1e-8f);
}

// ============================================================================
extern "C" void kernel_launch(void* const* d_in, const int* in_sizes, int n_in,
                              void* d_out, int out_size, void* d_ws, size_t ws_size,
                              hipStream_t stream) {
    const float* x   = (const float*)d_in[0];   // [4096,1024]
    const float* pw  = (const float*)d_in[1];   // [8,4096,1024]
    const float* Wd  = (const float*)d_in[2];   // [1,1024,1024]
    const float* S   = (const float*)d_in[3];   // [1,1024,1024] (numerically symmetric)
    const float* lam = (const float*)d_in[4];   // scalar
    const float* L   = (const float*)d_in[5];   // scalar
    float* out = (float*)d_out;                 // [512] ++ [4096*1024]

    float* b       = (float*)d_ws;                      // 4,194,304
    float* zatt    = b + (size_t)BATCH * DIM;           // 4,194,304
    float* pp_prev = zatt + (size_t)BATCH * DIM;        // 262,144
    float* pp_dens = pp_prev + 262144;                  // 32,768
    float* mD1     = pp_dens + 32768;                   // 512
    float* mD_prev = mD1 + 512;                         // 4096
    float* attw    = mD_prev + 4096;                    // 8
    float* mD2     = attw + 8;                          // 512
    float* sval1   = mD2 + 512;                         // 40,960
    float* sval2   = sval1 + 40960;                     // 40,960
    int*   sidx1   = (int*)(sval2 + 40960);             // 40,960 ints
    int*   sidx2   = sidx1 + 40960;                     // 40,960 ints

    float* c1   = out + 512;   // stage c1 in output z region (rewritten by loop_rows)
    float* zout = out + 512;

    const dim3 gg(DIM / 128, BATCH / 128);   // (8, 32)

    gemm128<true,  false><<<gg, 512, 0, stream>>>(x, Wd, nullptr, b, L, BATCH, DIM, DIM);
    warmup_rows<<<BATCH / 4, 256, 0, stream>>>(b, S, sidx1, sval1);
    sparse_density_stage1<<<64, 512, 0, stream>>>(sidx1, sval1, pp_dens);
    density_stage2<<<1, 512, 0, stream>>>(pp_dens, mD1);
    prev_density_stage1<<<dim3(PPREV, 64), 512, 0, stream>>>(pw, pp_prev);
    prev_density_stage2<<<PPREV, 512, 0, stream>>>(pp_prev, mD_prev);
    attention_small<<<1, 512, 0, stream>>>(mD1, mD_prev, attw);
    weighted_sum<<<(BATCH * DIM) / 1024, 256, 0, stream>>>(pw, attw, lam, zatt);
    gemm128<false, true ><<<gg, 512, 0, stream>>>(zatt, S, b, c1, nullptr, BATCH, DIM, DIM);
    loop_rows<<<BATCH / 4, 256, 0, stream>>>(c1, b, S, zout, sidx2, sval2);
    sparse_density_stage1<<<64, 512, 0, stream>>>(sidx2, sval2, pp_dens);
    density_stage2<<<1, 512, 0, stream>>>(pp_dens, mD2);
    finalize<<<1, 512, 0, stream>>>(mD2, out);
}